// Round 4
// baseline (165.363 us; speedup 1.0000x reference)
//
#include <hip/hip_runtime.h>

// EuclideanLoss: loss = (1/(B*N)) * sum_{b,n} w_n * sqrt(sum_d (x[b,n,d]-y[b,d,n])^2)
// w_n = 1.5 for n in {1,2}. B=32, N=8192, D=64, fp32. Memory-bound: 128 MiB moved.
//
// R3: R0/R2 were wave-level latency-bound: compiler kept VGPRs ~40 and
// interleaved load/wait/fma, so only ~2 loads in flight per wave (~3 TB/s
// effective). Fix: per-wave batch sized to fit registers (16 d: 4 float4 x +
// 16 scalar y = 32 data VGPRs) + an asm scheduling barrier so ALL 20 vmem
// instrs issue before any use (one waitcnt region, 8 KB in flight per wave).
// 4 waves/block each own a d-quarter of the same 64 n; partials via LDS.
// Grid (128,32)=4096 blocks = 64 waves/CU demanded, ~32 resident.

constexpr int B  = 32;
constexpr int N  = 8192;
constexpr int D  = 64;
constexpr int QD = D / 4;     // 16 d-elements per wave
constexpr int NPB = 64;       // n-values per block

__global__ __launch_bounds__(256, 4) void euclid_loss_kernel(
    const float* __restrict__ x,   // [B, N, D]
    const float* __restrict__ y,   // [B, D, N]
    float* __restrict__ out)       // [1]
{
    const int tid  = threadIdx.x;
    const int wave = tid >> 6;     // 0..3 = which d-quarter
    const int lane = tid & 63;
    const int n    = blockIdx.x * NPB + lane;
    const int b    = blockIdx.y;

    const float* xp = x + ((size_t)b * N + n) * D + wave * QD;
    const float* yp = y + (size_t)b * D * N + (size_t)(wave * QD) * N + n;

    // Load phase: 4 independent float4 (x, 16B/lane) + 16 independent scalar
    // (y, wave-coalesced 256B/instr). 32 data VGPRs.
    float4 xv[4];
#pragma unroll
    for (int j = 0; j < 4; ++j)
        xv[j] = *reinterpret_cast<const float4*>(xp + 4 * j);

    float yv[QD];
#pragma unroll
    for (int d = 0; d < QD; ++d)
        yv[d] = yp[(size_t)d * N];

    // Scheduling barrier: loads cannot sink past this -> all 20 vmem instrs
    // issue back-to-back, values held live -> full per-wave MLP.
    asm volatile("" ::: "memory");

    float acc = 0.0f;
#pragma unroll
    for (int j = 0; j < 4; ++j) {
        const float d0 = xv[j].x - yv[4 * j + 0];
        const float d1 = xv[j].y - yv[4 * j + 1];
        const float d2 = xv[j].z - yv[4 * j + 2];
        const float d3 = xv[j].w - yv[4 * j + 3];
        acc += d0 * d0 + d1 * d1 + d2 * d2 + d3 * d3;
    }

    // Combine the 4 d-quarters per n through LDS.
    __shared__ float part[4][NPB];
    part[wave][lane] = acc;        // 64 consecutive floats per wave: conflict-free
    __syncthreads();

    if (tid < NPB) {
        const float s = part[0][tid] + part[1][tid] + part[2][tid] + part[3][tid];
        const float w = (n == 1 || n == 2) ? 1.5f : 1.0f;   // n == blockIdx.x*64+tid here
        float v = w * __builtin_sqrtf(s);
#pragma unroll
        for (int off = 32; off > 0; off >>= 1) v += __shfl_down(v, off, 64);
        if (tid == 0)
            atomicAdd(out, v * (1.0f / (float)(B * N)));
    }
}

extern "C" void kernel_launch(void* const* d_in, const int* in_sizes, int n_in,
                              void* d_out, int out_size, void* d_ws, size_t ws_size,
                              hipStream_t stream) {
    const float* x = (const float*)d_in[0];
    const float* y = (const float*)d_in[1];
    float* out = (float*)d_out;

    // d_out is re-poisoned to 0xAA before every timed launch; zero it first.
    hipMemsetAsync(out, 0, sizeof(float), stream);

    dim3 grid(N / NPB, B);         // (128, 32) = 4096 blocks
    euclid_loss_kernel<<<grid, 256, 0, stream>>>(x, y, out);
}